// Round 1
// baseline (165.045 us; speedup 1.0000x reference)
//
#include <hip/hip_runtime.h>
#include <cfloat>

#define BDIM 256
constexpr int BB = 4096;    // batch
constexpr int CC = 50257;   // classes

// ---------------------------------------------------------------------------
// Kernel 1: per-row top-5 of x with x[row][y[row]] masked to 0, plus s_y.
// One block per row. Each thread keeps a sorted (descending) top-5 in
// registers; LDS tree merge across the block.
// ---------------------------------------------------------------------------
__global__ __launch_bounds__(BDIM) void topk_kernel(const float* __restrict__ x,
                                                    const int* __restrict__ y,
                                                    float* __restrict__ m_out,
                                                    float* __restrict__ sy_out) {
    const int row = blockIdx.x;
    const int tid = threadIdx.x;
    const float* __restrict__ xr = x + (size_t)row * CC;
    const int target = y[row];

    __shared__ float sy_sh;
    __shared__ float tl[BDIM][5];

    float t0 = -FLT_MAX, t1 = -FLT_MAX, t2 = -FLT_MAX, t3 = -FLT_MAX, t4 = -FLT_MAX;

#define INS(val)                                                        \
    do {                                                                \
        float _v = (val);                                               \
        if (_v > t4) {                                                  \
            t4 = _v;                                                    \
            if (t4 > t3) { float _w = t3; t3 = t4; t4 = _w; }           \
            if (t3 > t2) { float _w = t2; t2 = t3; t3 = _w; }           \
            if (t2 > t1) { float _w = t1; t1 = t2; t2 = _w; }           \
            if (t1 > t0) { float _w = t0; t0 = t1; t1 = _w; }           \
        }                                                               \
    } while (0)

#define PROC(jidx, raw)                                                 \
    do {                                                                \
        float _r = (raw);                                               \
        float _c = _r;                                                  \
        if ((jidx) == target) { sy_sh = _r; _c = 0.0f; }                \
        INS(_c);                                                        \
    } while (0)

    // Row base is only guaranteed 4B-aligned: (row*CC) % 4 == row % 4.
    const int align = (4 - (row & 3)) & 3;   // scalar elems before 16B boundary

    // prologue (align <= 3)
    if (tid < align) {
        PROC(tid, xr[tid]);
    }

    // vectorized body
    const int nvec = (CC - align) >> 2;
    const float4* __restrict__ xv = reinterpret_cast<const float4*>(xr + align);
    for (int i = tid; i < nvec; i += BDIM) {
        float4 v = xv[i];
        const int j0 = align + (i << 2);
        PROC(j0 + 0, v.x);
        PROC(j0 + 1, v.y);
        PROC(j0 + 2, v.z);
        PROC(j0 + 3, v.w);
    }

    // epilogue
    for (int j = align + (nvec << 2) + tid; j < CC; j += BDIM) {
        PROC(j, xr[j]);
    }

    tl[tid][0] = t0; tl[tid][1] = t1; tl[tid][2] = t2; tl[tid][3] = t3; tl[tid][4] = t4;
    __syncthreads();

    // deterministic tree merge of sorted 5-lists
    for (int s = BDIM / 2; s >= 1; s >>= 1) {
        if (tid < s) {
            float o0 = tl[tid + s][0], o1 = tl[tid + s][1], o2 = tl[tid + s][2],
                  o3 = tl[tid + s][3], o4 = tl[tid + s][4];
            INS(o0); INS(o1); INS(o2); INS(o3); INS(o4);
            tl[tid][0] = t0; tl[tid][1] = t1; tl[tid][2] = t2; tl[tid][3] = t3; tl[tid][4] = t4;
        }
        __syncthreads();
    }

    if (tid == 0) {
        m_out[row]  = (t0 + t1 + t2 + t3 + t4) * 0.2f;
        sy_out[row] = sy_sh;
    }
#undef PROC
#undef INS
}

// ---------------------------------------------------------------------------
// Kernel 2: partial[i] = sum_j relu(1 + m[j] - sy[i])   (the [B,B] broadcast)
// ---------------------------------------------------------------------------
__global__ __launch_bounds__(BDIM) void pair_kernel(const float* __restrict__ m,
                                                    const float* __restrict__ sy,
                                                    float* __restrict__ partial) {
    const int i = blockIdx.x;
    const int tid = threadIdx.x;
    const float syi = sy[i];
    float acc = 0.0f;
    for (int j = tid; j < BB; j += BDIM) {
        acc += fmaxf(1.0f + m[j] - syi, 0.0f);
    }
    __shared__ float red[BDIM];
    red[tid] = acc;
    __syncthreads();
    for (int s = BDIM / 2; s >= 1; s >>= 1) {
        if (tid < s) red[tid] += red[tid + s];
        __syncthreads();
    }
    if (tid == 0) partial[i] = red[0];
}

// ---------------------------------------------------------------------------
// Kernel 3: out = sum(partial) / (B*B)
// ---------------------------------------------------------------------------
__global__ __launch_bounds__(BDIM) void final_kernel(const float* __restrict__ partial,
                                                     float* __restrict__ out) {
    const int tid = threadIdx.x;
    float acc = 0.0f;
    for (int j = tid; j < BB; j += BDIM) acc += partial[j];
    __shared__ float red[BDIM];
    red[tid] = acc;
    __syncthreads();
    for (int s = BDIM / 2; s >= 1; s >>= 1) {
        if (tid < s) red[tid] += red[tid + s];
        __syncthreads();
    }
    if (tid == 0) out[0] = red[0] / 16777216.0f;  // B*B = 4096^2
}

extern "C" void kernel_launch(void* const* d_in, const int* in_sizes, int n_in,
                              void* d_out, int out_size, void* d_ws, size_t ws_size,
                              hipStream_t stream) {
    const float* x = (const float*)d_in[0];
    const int*   y = (const int*)d_in[1];
    float* out = (float*)d_out;

    float* m       = (float*)d_ws;     // [BB]
    float* sy      = m + BB;           // [BB]
    float* partial = sy + BB;          // [BB]

    topk_kernel<<<BB, BDIM, 0, stream>>>(x, y, m, sy);
    pair_kernel<<<BB, BDIM, 0, stream>>>(m, sy, partial);
    final_kernel<<<1, BDIM, 0, stream>>>(partial, out);
}

// Round 3
// 154.818 us; speedup vs baseline: 1.0661x; 1.0661x over previous
//
#include <hip/hip_runtime.h>
#include <cfloat>

#define BDIM 256
constexpr int BB = 4096;    // batch
constexpr int CC = 50257;   // classes

typedef float f32x4 __attribute__((ext_vector_type(4)));

// ---------------------------------------------------------------------------
// Kernel 1: per-row top-5 of x with x[row][y[row]] masked to 0, plus s_y.
// One block per row. Dual register top-5 accumulators per thread (breaks the
// loop-carried chain), nontemporal 2x float4 loads, target check hoisted to
// one range compare per float4. LDS tree merge across the block.
// ---------------------------------------------------------------------------
__global__ __launch_bounds__(BDIM) void topk_kernel(const float* __restrict__ x,
                                                    const int* __restrict__ y,
                                                    float* __restrict__ m_out,
                                                    float* __restrict__ sy_out) {
    const int row = blockIdx.x;
    const int tid = threadIdx.x;
    const float* __restrict__ xr = x + (size_t)row * CC;
    const int target = y[row];

    __shared__ float sy_sh;
    __shared__ float tl[BDIM][5];

    // accumulator A
    float a0 = -FLT_MAX, a1 = -FLT_MAX, a2 = -FLT_MAX, a3 = -FLT_MAX, a4 = -FLT_MAX;
    // accumulator B
    float b0 = -FLT_MAX, b1 = -FLT_MAX, b2 = -FLT_MAX, b3 = -FLT_MAX, b4 = -FLT_MAX;

#define INSA(val)                                                       \
    do {                                                                \
        float _v = (val);                                               \
        if (_v > a4) {                                                  \
            a4 = _v;                                                    \
            if (a4 > a3) { float _w = a3; a3 = a4; a4 = _w; }           \
            if (a3 > a2) { float _w = a2; a2 = a3; a3 = _w; }           \
            if (a2 > a1) { float _w = a1; a1 = a2; a2 = _w; }           \
            if (a1 > a0) { float _w = a0; a0 = a1; a1 = _w; }           \
        }                                                               \
    } while (0)

#define INSB(val)                                                       \
    do {                                                                \
        float _v = (val);                                               \
        if (_v > b4) {                                                  \
            b4 = _v;                                                    \
            if (b4 > b3) { float _w = b3; b3 = b4; b4 = _w; }           \
            if (b3 > b2) { float _w = b2; b2 = b3; b3 = _w; }           \
            if (b2 > b1) { float _w = b1; b1 = b2; b2 = _w; }           \
            if (b1 > b0) { float _w = b0; b0 = b1; b1 = _w; }           \
        }                                                               \
    } while (0)

    // Rare-path: mask target inside a float4 (native vec) whose base index is j0.
#define MASK4(vec, j0)                                                  \
    do {                                                                \
        int _d = target - (j0);                                         \
        if ((unsigned)_d < 4u) {                                        \
            sy_sh = (vec)[_d];                                          \
            (vec)[_d] = 0.0f;                                           \
        }                                                               \
    } while (0)

    // scalar edge handling (prologue/epilogue)
#define PROC(jidx, raw)                                                 \
    do {                                                                \
        float _r = (raw);                                               \
        float _c = _r;                                                  \
        if ((jidx) == target) { sy_sh = _r; _c = 0.0f; }                \
        INSA(_c);                                                       \
    } while (0)

    // Row base is only guaranteed 4B-aligned: (row*CC) % 4 == row % 4.
    const int align = (4 - (row & 3)) & 3;   // scalar elems before 16B boundary

    if (tid < align) {
        PROC(tid, xr[tid]);
    }

    const int nvec = (CC - align) >> 2;
    const f32x4* __restrict__ xv = reinterpret_cast<const f32x4*>(xr + align);

    int i = tid;
    // main body: two independent float4 loads per iteration
    for (; i + BDIM < nvec; i += 2 * BDIM) {
        f32x4 v0 = __builtin_nontemporal_load(&xv[i]);
        f32x4 v1 = __builtin_nontemporal_load(&xv[i + BDIM]);
        const int j0 = align + (i << 2);
        const int j1 = align + ((i + BDIM) << 2);
        MASK4(v0, j0);
        MASK4(v1, j1);
        INSA(v0[0]); INSB(v0[1]); INSA(v0[2]); INSB(v0[3]);
        INSA(v1[0]); INSB(v1[1]); INSA(v1[2]); INSB(v1[3]);
    }
    // remainder vector(s)
    for (; i < nvec; i += BDIM) {
        f32x4 v0 = __builtin_nontemporal_load(&xv[i]);
        const int j0 = align + (i << 2);
        MASK4(v0, j0);
        INSA(v0[0]); INSB(v0[1]); INSA(v0[2]); INSB(v0[3]);
    }

    // scalar epilogue
    for (int j = align + (nvec << 2) + tid; j < CC; j += BDIM) {
        PROC(j, xr[j]);
    }

    // merge B into A
    INSA(b0); INSA(b1); INSA(b2); INSA(b3); INSA(b4);

    tl[tid][0] = a0; tl[tid][1] = a1; tl[tid][2] = a2; tl[tid][3] = a3; tl[tid][4] = a4;
    __syncthreads();

    // deterministic tree merge of sorted 5-lists
    for (int s = BDIM / 2; s >= 1; s >>= 1) {
        if (tid < s) {
            float o0 = tl[tid + s][0], o1 = tl[tid + s][1], o2 = tl[tid + s][2],
                  o3 = tl[tid + s][3], o4 = tl[tid + s][4];
            INSA(o0); INSA(o1); INSA(o2); INSA(o3); INSA(o4);
            tl[tid][0] = a0; tl[tid][1] = a1; tl[tid][2] = a2; tl[tid][3] = a3; tl[tid][4] = a4;
        }
        __syncthreads();
    }

    if (tid == 0) {
        m_out[row]  = (a0 + a1 + a2 + a3 + a4) * 0.2f;
        sy_out[row] = sy_sh;
    }
#undef PROC
#undef MASK4
#undef INSA
#undef INSB
}

// ---------------------------------------------------------------------------
// Kernel 2: partial[i] = sum_j relu(1 + m[j] - sy[i])   (the [B,B] broadcast)
// ---------------------------------------------------------------------------
__global__ __launch_bounds__(BDIM) void pair_kernel(const float* __restrict__ m,
                                                    const float* __restrict__ sy,
                                                    float* __restrict__ partial) {
    const int i = blockIdx.x;
    const int tid = threadIdx.x;
    const float syi = sy[i];
    float acc = 0.0f;
    for (int j = tid; j < BB; j += BDIM) {
        acc += fmaxf(1.0f + m[j] - syi, 0.0f);
    }
    __shared__ float red[BDIM];
    red[tid] = acc;
    __syncthreads();
    for (int s = BDIM / 2; s >= 1; s >>= 1) {
        if (tid < s) red[tid] += red[tid + s];
        __syncthreads();
    }
    if (tid == 0) partial[i] = red[0];
}

// ---------------------------------------------------------------------------
// Kernel 3: out = sum(partial) / (B*B)
// ---------------------------------------------------------------------------
__global__ __launch_bounds__(BDIM) void final_kernel(const float* __restrict__ partial,
                                                     float* __restrict__ out) {
    const int tid = threadIdx.x;
    float acc = 0.0f;
    for (int j = tid; j < BB; j += BDIM) acc += partial[j];
    __shared__ float red[BDIM];
    red[tid] = acc;
    __syncthreads();
    for (int s = BDIM / 2; s >= 1; s >>= 1) {
        if (tid < s) red[tid] += red[tid + s];
        __syncthreads();
    }
    if (tid == 0) out[0] = red[0] / 16777216.0f;  // B*B = 4096^2
}

extern "C" void kernel_launch(void* const* d_in, const int* in_sizes, int n_in,
                              void* d_out, int out_size, void* d_ws, size_t ws_size,
                              hipStream_t stream) {
    const float* x = (const float*)d_in[0];
    const int*   y = (const int*)d_in[1];
    float* out = (float*)d_out;

    float* m       = (float*)d_ws;     // [BB]
    float* sy      = m + BB;           // [BB]
    float* partial = sy + BB;          // [BB]

    topk_kernel<<<BB, BDIM, 0, stream>>>(x, y, m, sy);
    pair_kernel<<<BB, BDIM, 0, stream>>>(m, sy, partial);
    final_kernel<<<1, BDIM, 0, stream>>>(partial, out);
}

// Round 4
// 152.350 us; speedup vs baseline: 1.0833x; 1.0162x over previous
//
#include <hip/hip_runtime.h>
#include <cfloat>

#define BDIM 256
constexpr int BB = 4096;    // batch
constexpr int CC = 50257;   // classes

typedef float f32x4 __attribute__((ext_vector_type(4)));

// ---------------------------------------------------------------------------
// Kernel 1: per-HALF-row top-5 (with target masked to 0) + s_y capture.
// Two blocks per row (grid = 2*BB) for finer scheduling granularity.
// Dual register top-5 accumulators per thread, 4x nontemporal float4 loads
// in flight, target check hoisted to one range compare per float4.
// Each block writes its sorted top-5 to ws; a tiny merge kernel combines.
// ---------------------------------------------------------------------------
__global__ __launch_bounds__(BDIM) void topk_half_kernel(const float* __restrict__ x,
                                                         const int* __restrict__ y,
                                                         float* __restrict__ t5_ws,
                                                         float* __restrict__ sy_out) {
    const int bid  = blockIdx.x;
    const int row  = bid >> 1;
    const int half = bid & 1;
    const int tid  = threadIdx.x;
    const float* __restrict__ xr = x + (size_t)row * CC;
    const int target = y[row];

    __shared__ float sy_sh;
    __shared__ float tl[BDIM][5];

    float a0 = -FLT_MAX, a1 = -FLT_MAX, a2 = -FLT_MAX, a3 = -FLT_MAX, a4 = -FLT_MAX;
    float b0 = -FLT_MAX, b1 = -FLT_MAX, b2 = -FLT_MAX, b3 = -FLT_MAX, b4 = -FLT_MAX;

#define INSA(val)                                                       \
    do {                                                                \
        float _v = (val);                                               \
        if (_v > a4) {                                                  \
            a4 = _v;                                                    \
            if (a4 > a3) { float _w = a3; a3 = a4; a4 = _w; }           \
            if (a3 > a2) { float _w = a2; a2 = a3; a3 = _w; }           \
            if (a2 > a1) { float _w = a1; a1 = a2; a2 = _w; }           \
            if (a1 > a0) { float _w = a0; a0 = a1; a1 = _w; }           \
        }                                                               \
    } while (0)

#define INSB(val)                                                       \
    do {                                                                \
        float _v = (val);                                               \
        if (_v > b4) {                                                  \
            b4 = _v;                                                    \
            if (b4 > b3) { float _w = b3; b3 = b4; b4 = _w; }           \
            if (b3 > b2) { float _w = b2; b2 = b3; b3 = _w; }           \
            if (b2 > b1) { float _w = b1; b1 = b2; b2 = _w; }           \
            if (b1 > b0) { float _w = b0; b0 = b1; b1 = _w; }           \
        }                                                               \
    } while (0)

#define MASK4(vec, j0)                                                  \
    do {                                                                \
        int _d = target - (j0);                                         \
        if ((unsigned)_d < 4u) {                                        \
            sy_sh = (vec)[_d];                                          \
            (vec)[_d] = 0.0f;                                           \
        }                                                               \
    } while (0)

#define PROC(jidx, raw)                                                 \
    do {                                                                \
        float _r = (raw);                                               \
        float _c = _r;                                                  \
        if ((jidx) == target) { sy_sh = _r; _c = 0.0f; }                \
        INSA(_c);                                                       \
    } while (0)

    // Row base is only 4B-aligned: (row*CC) % 4 == row % 4.
    const int align = (4 - (row & 3)) & 3;
    const int nvec  = (CC - align) >> 2;
    const int halfv = nvec >> 1;
    const int vbeg  = half ? halfv : 0;
    const int vend  = half ? nvec  : halfv;

    // scalar edges: prologue belongs to half 0, epilogue to half 1
    if (!half) {
        if (tid < align) PROC(tid, xr[tid]);
    } else {
        for (int j = align + (nvec << 2) + tid; j < CC; j += BDIM) PROC(j, xr[j]);
    }

    const f32x4* __restrict__ xv = reinterpret_cast<const f32x4*>(xr + align);

    int i = vbeg + tid;
    // main body: four independent float4 loads per iteration
    for (; i + 3 * BDIM < vend; i += 4 * BDIM) {
        f32x4 v0 = __builtin_nontemporal_load(&xv[i]);
        f32x4 v1 = __builtin_nontemporal_load(&xv[i + BDIM]);
        f32x4 v2 = __builtin_nontemporal_load(&xv[i + 2 * BDIM]);
        f32x4 v3 = __builtin_nontemporal_load(&xv[i + 3 * BDIM]);
        const int j0 = align + (i << 2);
        const int j1 = align + ((i + BDIM) << 2);
        const int j2 = align + ((i + 2 * BDIM) << 2);
        const int j3 = align + ((i + 3 * BDIM) << 2);
        MASK4(v0, j0); MASK4(v1, j1); MASK4(v2, j2); MASK4(v3, j3);
        INSA(v0[0]); INSB(v0[1]); INSA(v0[2]); INSB(v0[3]);
        INSA(v1[0]); INSB(v1[1]); INSA(v1[2]); INSB(v1[3]);
        INSA(v2[0]); INSB(v2[1]); INSA(v2[2]); INSB(v2[3]);
        INSA(v3[0]); INSB(v3[1]); INSA(v3[2]); INSB(v3[3]);
    }
    for (; i < vend; i += BDIM) {
        f32x4 v0 = __builtin_nontemporal_load(&xv[i]);
        const int j0 = align + (i << 2);
        MASK4(v0, j0);
        INSA(v0[0]); INSB(v0[1]); INSA(v0[2]); INSB(v0[3]);
    }

    INSA(b0); INSA(b1); INSA(b2); INSA(b3); INSA(b4);

    tl[tid][0] = a0; tl[tid][1] = a1; tl[tid][2] = a2; tl[tid][3] = a3; tl[tid][4] = a4;
    __syncthreads();

    for (int s = BDIM / 2; s >= 1; s >>= 1) {
        if (tid < s) {
            float o0 = tl[tid + s][0], o1 = tl[tid + s][1], o2 = tl[tid + s][2],
                  o3 = tl[tid + s][3], o4 = tl[tid + s][4];
            INSA(o0); INSA(o1); INSA(o2); INSA(o3); INSA(o4);
            tl[tid][0] = a0; tl[tid][1] = a1; tl[tid][2] = a2; tl[tid][3] = a3; tl[tid][4] = a4;
        }
        __syncthreads();
    }

    if (tid == 0) {
        float* t5 = t5_ws + (size_t)bid * 5;
        t5[0] = a0; t5[1] = a1; t5[2] = a2; t5[3] = a3; t5[4] = a4;
        // does this block's range contain the target?
        const int lo = half ? align + (halfv << 2) : 0;
        const int hi = half ? CC : align + (halfv << 2);
        if (target >= lo && target < hi) sy_out[row] = sy_sh;
    }
#undef PROC
#undef MASK4
#undef INSA
#undef INSB
}

// ---------------------------------------------------------------------------
// Kernel 2: merge the two sorted 5-lists per row -> m[row] = mean(top5)
// ---------------------------------------------------------------------------
__global__ __launch_bounds__(BDIM) void merge_kernel(const float* __restrict__ t5_ws,
                                                     float* __restrict__ m_out) {
    const int r = blockIdx.x * BDIM + threadIdx.x;
    if (r >= BB) return;
    const float* __restrict__ p = t5_ws + (size_t)r * 10;
    const float* A = p;
    const float* B = p + 5;
    float s = 0.0f;
    int ia = 0, ib = 0;
    #pragma unroll
    for (int k = 0; k < 5; ++k) {
        float av = A[ia], bv = B[ib];
        if (av >= bv) { s += av; ++ia; }
        else          { s += bv; ++ib; }
    }
    m_out[r] = s * 0.2f;
}

// ---------------------------------------------------------------------------
// Kernel 3: partial[i] = sum_j relu(1 + m[j] - sy[i])
// ---------------------------------------------------------------------------
__global__ __launch_bounds__(BDIM) void pair_kernel(const float* __restrict__ m,
                                                    const float* __restrict__ sy,
                                                    float* __restrict__ partial) {
    const int i = blockIdx.x;
    const int tid = threadIdx.x;
    const float syi = sy[i];
    float acc = 0.0f;
    for (int j = tid; j < BB; j += BDIM) {
        acc += fmaxf(1.0f + m[j] - syi, 0.0f);
    }
    __shared__ float red[BDIM];
    red[tid] = acc;
    __syncthreads();
    for (int s = BDIM / 2; s >= 1; s >>= 1) {
        if (tid < s) red[tid] += red[tid + s];
        __syncthreads();
    }
    if (tid == 0) partial[i] = red[0];
}

// ---------------------------------------------------------------------------
// Kernel 4: out = sum(partial) / (B*B)
// ---------------------------------------------------------------------------
__global__ __launch_bounds__(BDIM) void final_kernel(const float* __restrict__ partial,
                                                     float* __restrict__ out) {
    const int tid = threadIdx.x;
    float acc = 0.0f;
    for (int j = tid; j < BB; j += BDIM) acc += partial[j];
    __shared__ float red[BDIM];
    red[tid] = acc;
    __syncthreads();
    for (int s = BDIM / 2; s >= 1; s >>= 1) {
        if (tid < s) red[tid] += red[tid + s];
        __syncthreads();
    }
    if (tid == 0) out[0] = red[0] / 16777216.0f;  // B*B = 4096^2
}

extern "C" void kernel_launch(void* const* d_in, const int* in_sizes, int n_in,
                              void* d_out, int out_size, void* d_ws, size_t ws_size,
                              hipStream_t stream) {
    const float* x = (const float*)d_in[0];
    const int*   y = (const int*)d_in[1];
    float* out = (float*)d_out;

    float* t5      = (float*)d_ws;        // [2*BB*5]
    float* sy      = t5 + 2 * BB * 5;     // [BB]
    float* m       = sy + BB;             // [BB]
    float* partial = m + BB;              // [BB]

    topk_half_kernel<<<2 * BB, BDIM, 0, stream>>>(x, y, t5, sy);
    merge_kernel<<<BB / BDIM, BDIM, 0, stream>>>(t5, m);
    pair_kernel<<<BB, BDIM, 0, stream>>>(m, sy, partial);
    final_kernel<<<1, BDIM, 0, stream>>>(partial, out);
}